// Round 1
// 423.232 us; speedup vs baseline: 1.1738x; 1.1738x over previous
//
#include <hip/hip_runtime.h>
#include <stdint.h>

// Problem constants
#define DM   2048
#define NH   16
#define HD   128
#define BB   2
#define SS   2048
#define MM   (BB*SS)     // 4096
#define KK   2048
#define NQKV (3*DM)      // 6144

#define LOG2E  1.4426950408889634f
#define SCALE  0.08838834764831845f   // 1/sqrt(128)

using bf16x8 = __attribute__((ext_vector_type(8))) __bf16;
using f32x4  = __attribute__((ext_vector_type(4))) float;
typedef unsigned short u16;
typedef unsigned int   u32;

__device__ __forceinline__ u16 f2bf(float f) {
  u32 u = __float_as_uint(f);
  u32 r = (u + 0x7FFFu + ((u >> 16) & 1u)) >> 16;   // RNE
  return (u16)r;
}

// async global->LDS, 16B per lane. LDS dest must be lane-contiguous (base+tid*16).
__device__ __forceinline__ void load_lds16(const void* g, void* l) {
  __builtin_amdgcn_global_load_lds(
      (__attribute__((address_space(1))) void*)(g),
      (__attribute__((address_space(3))) void*)(l), 16, 0, 0);
}

// ---------------- cast fp32 -> bf16 (4 elems/thread) ----------------
__global__ void cast_f32_bf16(const float* __restrict__ s, u16* __restrict__ d, int n) {
  int i = (blockIdx.x * blockDim.x + threadIdx.x) * 4;
  if (i < n) {
    float4 f = *(const float4*)(s + i);
    u32 lo = (u32)f2bf(f.x) | ((u32)f2bf(f.y) << 16);
    u32 hi = (u32)f2bf(f.z) | ((u32)f2bf(f.w) << 16);
    *(uint2*)(d + i) = make_uint2(lo, hi);
  }
}

// ---------------- "RoPE" factor table ----------------
// Reference's _rotate_half is the identity (splits 128-dim head at 128).
// q <- q*(cos+sin) elementwise. f[s][j] = cos(s*inv[j&63]) + sin(s*inv[j&63]).
__global__ void rope_fct(float* __restrict__ f) {
  int i = blockIdx.x * blockDim.x + threadIdx.x;   // SS*128 threads
  if (i < SS * 128) {
    int s = i >> 7, j = i & 127;
    double inv = pow(10000.0, -(double)(j & 63) / 64.0);
    float ang = (float)s * (float)inv;
    float sn, cs;
    sincosf(ang, &sn, &cs);
    f[i] = cs + sn;
  }
}

// ---------------- QKV GEMM (M=4096, N=6144, K=2048) + fused q/k scaling -----
// A: x bf16 (M x K row-major). Bm: [Wq;Wk;Wv] bf16 (N x K row-major).
__global__ __launch_bounds__(256, 2)
void gemm_qkv_rope(const u16* __restrict__ A, const u16* __restrict__ Bm,
                   u16* __restrict__ qo, u16* __restrict__ ko, u16* __restrict__ vo,
                   const float* __restrict__ fct) {
  __shared__ __align__(16) u16 S[2][128 * 32];   // As=S[0], Bs=S[1]; 16KB total
  u16* As = S[0];
  u16* Bs = S[1];
  const int tid = threadIdx.x;
  const int w = tid >> 6, lane = tid & 63, ln = lane & 15, quad = lane >> 4;
  const int m0 = blockIdx.x * 128, n0 = blockIdx.y * 128;

  const f32x4 fz = {0.f, 0.f, 0.f, 0.f};
  f32x4 acc[2][8];
#pragma unroll
  for (int mt = 0; mt < 2; mt++)
#pragma unroll
    for (int nt = 0; nt < 8; nt++) acc[mt][nt] = fz;

  for (int k0 = 0; k0 < KK; k0 += 32) {
    __syncthreads();
#pragma unroll
    for (int i = 0; i < 2; i++) {
      int tt = i * 256 + tid;
      load_lds16(A + (size_t)(m0 + (tt >> 2)) * KK + k0 + (tt & 3) * 8, (char*)As + tt * 16);
    }
#pragma unroll
    for (int i = 0; i < 2; i++) {
      int tt = i * 256 + tid;
      load_lds16(Bm + (size_t)(n0 + (tt >> 2)) * KK + k0 + (tt & 3) * 8, (char*)Bs + tt * 16);
    }
    __syncthreads();
    bf16x8 af[2];
#pragma unroll
    for (int mt = 0; mt < 2; mt++)
      af[mt] = *(const bf16x8*)&As[(w * 32 + mt * 16 + ln) * 32 + quad * 8];
#pragma unroll
    for (int nt = 0; nt < 8; nt++) {
      bf16x8 bf = *(const bf16x8*)&Bs[(nt * 16 + ln) * 32 + quad * 8];
#pragma unroll
      for (int mt = 0; mt < 2; mt++)
        acc[mt][nt] = __builtin_amdgcn_mfma_f32_16x16x32_bf16(af[mt], bf, acc[mt][nt], 0, 0, 0);
    }
  }

  // Epilogue. Block's N-range is exactly one (tensor, head).
  const int tensor = n0 >> 11;          // 0:q 1:k 2:v
  const int h = (n0 & 2047) >> 7;
  if (tensor < 2) {
    u16* dst = (tensor == 0) ? qo : ko;
#pragma unroll
    for (int mt = 0; mt < 2; mt++)
#pragma unroll
      for (int r = 0; r < 4; r++) {
        int m = m0 + w * 32 + mt * 16 + quad * 4 + r;
        int b = m >> 11, s = m & 2047;
        size_t base = ((size_t)(b * NH + h) * SS + s) * HD;
        const float* fr = fct + s * 128;
#pragma unroll
        for (int nt = 0; nt < 8; nt++) {
          int j = nt * 16 + ln;
          dst[base + j] = f2bf(acc[mt][nt][r] * fr[j]);
        }
      }
  } else {
    // V: transpose via LDS (reuse staging buffers), coalesced 16B stores to (B,NH,HD,S)
    u16* Tr = (u16*)S;                  // 16KB: 128 hd x 64 compressed-s, swizzled
    const int b = m0 >> 11, s0 = m0 & 2047;
#pragma unroll
    for (int mt = 0; mt < 2; mt++) {
      __syncthreads();                  // Tr region free of previous readers
#pragma unroll
      for (int nt = 0; nt < 8; nt++) {
        int hd = nt * 16 + ln;
#pragma unroll
        for (int r = 0; r < 4; r++) {
          int c = w * 16 + quad * 4 + r;   // compressed s-index 0..63
          Tr[hd * 64 + (((c >> 3) ^ (hd & 7)) * 8) + (c & 7)] = f2bf(acc[mt][nt][r]);
        }
      }
      __syncthreads();
#pragma unroll
      for (int it = 0; it < 4; it++) {
        int idx = it * 256 + tid;
        int hd = idx >> 3, c8 = idx & 7;
        uint4 val = *(const uint4*)&Tr[hd * 64 + ((c8 ^ (hd & 7)) * 8)];
        int c0 = c8 * 8;
        int srel = ((c0 >> 4) * 32) + mt * 16 + (c0 & 15);
        *(uint4*)(vo + ((size_t)(b * NH + h) * HD + hd) * SS + s0 + srel) = val;
      }
    }
  }
}

// ---------------- Flash attention v4 ----------------
// grid (16, NH, B) = 512 blocks, 2 blocks/CU (LDS 72KB, launch_bounds(256,2)).
// Block bx handles 64-row q-tiles {bx, 31-bx} -> uniform 33 k-tile units/block.
// Q loaded direct global->registers (no LDS staging). K/V double-buffered,
// XOR-swizzled LDS for conflict-free ds_read_b128. P buffer 8KB, wave-private.
__global__ __launch_bounds__(256, 2)
void flash_attn(const u16* __restrict__ q, const u16* __restrict__ k,
                const u16* __restrict__ v, u16* __restrict__ o) {
  __shared__ __align__(16) u16 Ps[64 * 64];       // 8KB: P (wave-private 16-row slabs)
  __shared__ __align__(16) u16 Ks[2][64 * 128];   // 2 x 16KB
  __shared__ __align__(16) u16 Vs[2][128 * 64];   // 2 x 16KB (Vt: hd rows, k cols)
  const int tid = threadIdx.x;
  const int w = tid >> 6, lane = tid & 63, ln = lane & 15, quad = lane >> 4;
  const int hh = blockIdx.y, b = blockIdx.z;
  const size_t bh = (size_t)b * NH + hh;
  const u16* Kg = k + bh * SS * HD;
  const u16* Vg = v + bh * HD * SS;

  for (int half = 0; half < 2; half++) {
    const int T = half ? (31 - (int)blockIdx.x) : (int)blockIdx.x;
    const u16* Qg = q + bh * SS * HD + (size_t)T * 64 * HD;

    // Q -> registers, direct from global (read once; 4 x 16B/lane)
    bf16x8 qf[4];
#pragma unroll
    for (int kc = 0; kc < 4; kc++)
      qf[kc] = *(const bf16x8*)(Qg + (size_t)(w * 16 + ln) * HD + (kc * 4 + quad) * 8);

    __syncthreads();   // Ks/Vs free of previous tile's readers

    // prefetch kt=0 into buffer 0
#pragma unroll
    for (int i = 0; i < 4; i++) {
      int slot = i * 256 + tid;
      int r = slot >> 4, c = (slot & 15) ^ (r & 7);
      load_lds16(Kg + (size_t)r * HD + c * 8, (char*)Ks[0] + slot * 16);
    }
#pragma unroll
    for (int i = 0; i < 4; i++) {
      int slot = i * 256 + tid;
      int r = slot >> 3, c = (slot & 7) ^ (r & 7);
      load_lds16(Vg + (size_t)r * SS + c * 8, (char*)Vs[0] + slot * 16);
    }

    const f32x4 fz = {0.f, 0.f, 0.f, 0.f};
    float m_s[4], l_s[4];
    f32x4 accO[8];
#pragma unroll
    for (int r = 0; r < 4; r++) { m_s[r] = -1e30f; l_s[r] = 0.f; }
#pragma unroll
    for (int nt = 0; nt < 8; nt++) accO[nt] = fz;

    const int nkt = T + 1;
    const int qrb = T * 64 + w * 16;

    for (int kt = 0; kt < nkt; kt++) {
      const int cur = kt & 1;
      const int k0 = kt * 64;
      // drain the staging issued one iteration ago (latency already hidden)
      __asm__ __volatile__("s_waitcnt vmcnt(0)" ::: "memory");
      __syncthreads();
      if (kt + 1 < nkt) {   // prefetch next k-tile into the other buffer
        const int kn = k0 + 64;
#pragma unroll
        for (int i = 0; i < 4; i++) {
          int slot = i * 256 + tid;
          int r = slot >> 4, c = (slot & 15) ^ (r & 7);
          load_lds16(Kg + (size_t)(kn + r) * HD + c * 8, (char*)Ks[cur ^ 1] + slot * 16);
        }
#pragma unroll
        for (int i = 0; i < 4; i++) {
          int slot = i * 256 + tid;
          int r = slot >> 3, c = (slot & 7) ^ (r & 7);
          load_lds16(Vg + (size_t)r * SS + kn + c * 8, (char*)Vs[cur ^ 1] + slot * 16);
        }
      }

      // S = Q K^T  (16 q-rows x 64 k-cols per wave)
      f32x4 sc[4];
#pragma unroll
      for (int nt = 0; nt < 4; nt++) sc[nt] = fz;
#pragma unroll
      for (int kc = 0; kc < 4; kc++)
#pragma unroll
        for (int nt = 0; nt < 4; nt++) {
          bf16x8 bf = *(const bf16x8*)&Ks[cur][(nt * 16 + ln) * 128 + (((kc * 4 + quad) ^ (ln & 7)) * 8)];
          sc[nt] = __builtin_amdgcn_mfma_f32_16x16x32_bf16(qf[kc], bf, sc[nt], 0, 0, 0);
        }

      const bool partial = (kt == T);
#pragma unroll
      for (int nt = 0; nt < 4; nt++)
#pragma unroll
        for (int r = 0; r < 4; r++) {
          float val = sc[nt][r] * SCALE;
          if (partial && (k0 + nt * 16 + ln > qrb + quad * 4 + r)) val = -1e9f;
          sc[nt][r] = val;
        }

      // online softmax per row
#pragma unroll
      for (int r = 0; r < 4; r++) {
        float mx = fmaxf(fmaxf(sc[0][r], sc[1][r]), fmaxf(sc[2][r], sc[3][r]));
#pragma unroll
        for (int off = 1; off < 16; off <<= 1) mx = fmaxf(mx, __shfl_xor(mx, off));
        float mnew = fmaxf(m_s[r], mx);
        float alpha = exp2f((m_s[r] - mnew) * LOG2E);
        float rs = 0.f;
#pragma unroll
        for (int nt = 0; nt < 4; nt++) {
          float p = exp2f((sc[nt][r] - mnew) * LOG2E);
          sc[nt][r] = p;
          rs += p;
        }
#pragma unroll
        for (int off = 1; off < 16; off <<= 1) rs += __shfl_xor(rs, off);
        l_s[r] = l_s[r] * alpha + rs;
        m_s[r] = mnew;
#pragma unroll
        for (int nt = 0; nt < 8; nt++) accO[nt][r] *= alpha;
      }

      // P: C-layout -> LDS (swizzled, wave-private 16-row slab) -> A-layout
#pragma unroll
      for (int nt = 0; nt < 4; nt++)
#pragma unroll
        for (int r = 0; r < 4; r++) {
          int rr = w * 16 + quad * 4 + r;
          int j = nt * 16 + ln;
          Ps[rr * 64 + (((j >> 3) ^ (rr & 7)) * 8) + (j & 7)] = f2bf(sc[nt][r]);
        }
      __asm__ __volatile__("s_waitcnt lgkmcnt(0)" ::: "memory");

      bf16x8 pf[2];
#pragma unroll
      for (int kc = 0; kc < 2; kc++) {
        int rp = w * 16 + ln;
        pf[kc] = *(const bf16x8*)&Ps[rp * 64 + (((kc * 4 + quad) ^ (ln & 7)) * 8)];
      }

      // O += P V
#pragma unroll
      for (int kc = 0; kc < 2; kc++)
#pragma unroll
        for (int nt = 0; nt < 8; nt++) {
          bf16x8 vf = *(const bf16x8*)&Vs[cur][(nt * 16 + ln) * 64 + (((kc * 4 + quad) ^ (ln & 7)) * 8)];
          accO[nt] = __builtin_amdgcn_mfma_f32_16x16x32_bf16(pf[kc], vf, accO[nt], 0, 0, 0);
        }
    }

    // normalize + store (B, S, DM) bf16
#pragma unroll
    for (int r = 0; r < 4; r++) {
      float ilv = 1.f / l_s[r];
      int srow = T * 64 + w * 16 + quad * 4 + r;
      size_t base = ((size_t)b * SS + srow) * DM + hh * HD;
#pragma unroll
      for (int nt = 0; nt < 8; nt++)
        o[base + nt * 16 + ln] = f2bf(accO[nt][r] * ilv);
    }
  }
}

// ---------------- Output GEMM (M=4096, N=2048, K=2048), fp32 epilogue --------
__global__ __launch_bounds__(256, 2)
void gemm_out(const u16* __restrict__ A, const u16* __restrict__ Bm,
              float* __restrict__ C) {
  __shared__ __align__(16) u16 As[128 * 32];
  __shared__ __align__(16) u16 Bs[128 * 32];
  const int tid = threadIdx.x;
  const int w = tid >> 6, lane = tid & 63, ln = lane & 15, quad = lane >> 4;
  const int m0 = blockIdx.x * 128, n0 = blockIdx.y * 128;

  const f32x4 fz = {0.f, 0.f, 0.f, 0.f};
  f32x4 acc[2][8];
#pragma unroll
  for (int mt = 0; mt < 2; mt++)
#pragma unroll
    for (int nt = 0; nt < 8; nt++) acc[mt][nt] = fz;

  for (int k0 = 0; k0 < KK; k0 += 32) {
    __syncthreads();
#pragma unroll
    for (int i = 0; i < 2; i++) {
      int tt = i * 256 + tid;
      load_lds16(A + (size_t)(m0 + (tt >> 2)) * KK + k0 + (tt & 3) * 8, (char*)As + tt * 16);
    }
#pragma unroll
    for (int i = 0; i < 2; i++) {
      int tt = i * 256 + tid;
      load_lds16(Bm + (size_t)(n0 + (tt >> 2)) * KK + k0 + (tt & 3) * 8, (char*)Bs + tt * 16);
    }
    __syncthreads();
    bf16x8 af[2];
#pragma unroll
    for (int mt = 0; mt < 2; mt++)
      af[mt] = *(const bf16x8*)&As[(w * 32 + mt * 16 + ln) * 32 + quad * 8];
#pragma unroll
    for (int nt = 0; nt < 8; nt++) {
      bf16x8 bf = *(const bf16x8*)&Bs[(nt * 16 + ln) * 32 + quad * 8];
#pragma unroll
      for (int mt = 0; mt < 2; mt++)
        acc[mt][nt] = __builtin_amdgcn_mfma_f32_16x16x32_bf16(af[mt], bf, acc[mt][nt], 0, 0, 0);
    }
  }

#pragma unroll
  for (int mt = 0; mt < 2; mt++)
#pragma unroll
    for (int r = 0; r < 4; r++) {
      int m = m0 + w * 32 + mt * 16 + quad * 4 + r;
#pragma unroll
      for (int nt = 0; nt < 8; nt++)
        C[(size_t)m * DM + n0 + nt * 16 + ln] = acc[mt][nt][r];
    }
}

// ---------------- launch ----------------
extern "C" void kernel_launch(void* const* d_in, const int* in_sizes, int n_in,
                              void* d_out, int out_size, void* d_ws, size_t ws_size,
                              hipStream_t stream) {
  (void)in_sizes; (void)n_in; (void)out_size; (void)ws_size;
  const float* x  = (const float*)d_in[0];
  // d_in[1] = attention_mask (exact causal tril) — implemented analytically
  const float* Wq = (const float*)d_in[2];
  const float* Wk = (const float*)d_in[3];
  const float* Wv = (const float*)d_in[4];
  const float* Wd = (const float*)d_in[5];

  // Workspace (96 MiB):
  //   [0,16M) xb (reused as aob)  [16M,40M) wqkv  [40M..] fct then wdb
  //   [48M,64M) qb  [64M,80M) kb  [80M,96M) vtb
  char* ws = (char*)d_ws;
  u16* xb   = (u16*)(ws);
  u16* aob  = xb;
  u16* wqkv = (u16*)(ws + 16777216ull);
  float* fct = (float*)(ws + 41943040ull);
  u16* wdb  = (u16*)(ws + 41943040ull);
  u16* qb   = (u16*)(ws + 50331648ull);
  u16* kb   = (u16*)(ws + 67108864ull);
  u16* vtb  = (u16*)(ws + 83886080ull);

  cast_f32_bf16<<<8192, 256, 0, stream>>>(x,  xb, MM * KK);
  cast_f32_bf16<<<4096, 256, 0, stream>>>(Wq, wqkv,                   DM * KK);
  cast_f32_bf16<<<4096, 256, 0, stream>>>(Wk, wqkv + (size_t)DM*KK,   DM * KK);
  cast_f32_bf16<<<4096, 256, 0, stream>>>(Wv, wqkv + (size_t)2*DM*KK, DM * KK);
  rope_fct<<<1024, 256, 0, stream>>>(fct);

  gemm_qkv_rope<<<dim3(MM / 128, NQKV / 128), 256, 0, stream>>>(xb, wqkv, qb, kb, vtb, fct);

  cast_f32_bf16<<<4096, 256, 0, stream>>>(Wd, wdb, DM * KK);   // overwrites fct (dead)

  flash_attn<<<dim3(16, NH, BB), 256, 0, stream>>>(qb, kb, vtb, aob);
  gemm_out<<<dim3(MM / 128, DM / 128), 256, 0, stream>>>(aob, wdb, (float*)d_out);
}

// Round 2
// 408.990 us; speedup vs baseline: 1.2147x; 1.0348x over previous
//
#include <hip/hip_runtime.h>
#include <stdint.h>

// Problem constants
#define DM   2048
#define NH   16
#define HD   128
#define BB   2
#define SS   2048
#define MM   (BB*SS)     // 4096
#define KK   2048
#define NQKV (3*DM)      // 6144

#define LOG2E  1.4426950408889634f
#define SCALE  0.08838834764831845f   // 1/sqrt(128)

using bf16x8 = __attribute__((ext_vector_type(8))) __bf16;
using f32x4  = __attribute__((ext_vector_type(4))) float;
typedef unsigned short u16;
typedef unsigned int   u32;

__device__ __forceinline__ u16 f2bf(float f) {
  u32 u = __float_as_uint(f);
  u32 r = (u + 0x7FFFu + ((u >> 16) & 1u)) >> 16;   // RNE
  return (u16)r;
}

// async global->LDS, 16B per lane. LDS dest must be lane-contiguous (base+tid*16).
__device__ __forceinline__ void load_lds16(const void* g, void* l) {
  __builtin_amdgcn_global_load_lds(
      (__attribute__((address_space(1))) void*)(g),
      (__attribute__((address_space(3))) void*)(l), 16, 0, 0);
}

// ---------------- cast fp32 -> bf16 (4 elems/thread) ----------------
__global__ void cast_f32_bf16(const float* __restrict__ s, u16* __restrict__ d, int n) {
  int i = (blockIdx.x * blockDim.x + threadIdx.x) * 4;
  if (i < n) {
    float4 f = *(const float4*)(s + i);
    u32 lo = (u32)f2bf(f.x) | ((u32)f2bf(f.y) << 16);
    u32 hi = (u32)f2bf(f.z) | ((u32)f2bf(f.w) << 16);
    *(uint2*)(d + i) = make_uint2(lo, hi);
  }
}

// ---------------- "RoPE" factor table ----------------
// Reference's _rotate_half is the identity (splits 128-dim head at 128).
// q <- q*(cos+sin) elementwise. f[s][j] = cos(s*inv[j&63]) + sin(s*inv[j&63]).
__global__ void rope_fct(float* __restrict__ f) {
  int i = blockIdx.x * blockDim.x + threadIdx.x;   // SS*128 threads
  if (i < SS * 128) {
    int s = i >> 7, j = i & 127;
    double inv = pow(10000.0, -(double)(j & 63) / 64.0);
    float ang = (float)s * (float)inv;
    float sn, cs;
    sincosf(ang, &sn, &cs);
    f[i] = cs + sn;
  }
}

// ---------------- QKV GEMM v2: 256x256 tile, BK=64, 8-phase counted-vmcnt ----
// A: x bf16 (M x K row-major). Bm: [Wq;Wk;Wv] bf16 (N x K row-major).
// 512 threads = 8 waves (2M x 4N). Wave tile 128x64, interleaved across tile
// halves: wave rows {wm*64..+64} u {128+wm*64..+64}, cols {wn*32..+32} u
// {128+wn*32..+32} -> every wave reads all 4 half-tiles, enabling vmcnt(4)
// (2 half-tiles in flight past the needed one; never vmcnt(0) in main loop).
// Per K-tile: 4 phases, each = {ds_read frags | stage 1 half-tile of t+1 |
// barrier; lgkmcnt(0); setprio(1); 16 MFMA; setprio(0)}.
// LDS 128KB: [buf][A/B][256*64] bf16, chunk-XOR swizzle (c^(r&7)) applied by
// pre-swizzling the global source (gload_lds dest must stay linear).

__device__ __forceinline__ void stage_half(const u16* __restrict__ G, int rowbase,
                                           int kbase, int h, u16* lds, int tid) {
#pragma unroll
  for (int i = 0; i < 2; i++) {
    int s = i * 512 + tid;
    int r = s >> 3, c = s & 7;
    load_lds16(G + (size_t)(rowbase + h * 128 + r) * KK + kbase + ((c ^ (r & 7)) * 8),
               (char*)lds + (size_t)(h * 1024 + s) * 16);
  }
}

__global__ __launch_bounds__(512, 2)
void gemm_qkv_rope(const u16* __restrict__ A, const u16* __restrict__ Bm,
                   u16* __restrict__ qo, u16* __restrict__ ko, u16* __restrict__ vo,
                   const float* __restrict__ fct) {
  __shared__ __align__(16) u16 L[2][2][256 * 64];   // 128 KB
  const int tid = threadIdx.x;
  const int wid = tid >> 6, lane = tid & 63, ln = lane & 15, quad = lane >> 4;
  const int wm = wid >> 2, wn = wid & 3;
  const int m0 = blockIdx.x * 256, n0 = blockIdx.y * 256;

  const f32x4 fz = {0.f, 0.f, 0.f, 0.f};
  f32x4 acc[8][4];
#pragma unroll
  for (int mi = 0; mi < 8; mi++)
#pragma unroll
    for (int ni = 0; ni < 4; ni++) acc[mi][ni] = fz;

  // wave-local row indices (within 256-row LDS tiles); ln baked in for ds_read
  int aRow[8], bRow[4];
#pragma unroll
  for (int mi = 0; mi < 8; mi++)
    aRow[mi] = ((mi < 4) ? (wm * 64 + mi * 16) : (128 + wm * 64 + (mi - 4) * 16)) + ln;
#pragma unroll
  for (int ni = 0; ni < 4; ni++)
    bRow[ni] = ((ni < 2) ? (wn * 32 + ni * 16) : (128 + wn * 32 + (ni - 2) * 16)) + ln;

  // prologue: stage tile 0 into buf 0, order A0,B0,A1,B1 (matches per-phase order)
  stage_half(A,  m0, 0, 0, L[0][0], tid);
  stage_half(Bm, n0, 0, 0, L[0][1], tid);
  stage_half(A,  m0, 0, 1, L[0][0], tid);
  stage_half(Bm, n0, 0, 1, L[0][1], tid);

  const int nT = KK / 64;   // 32
  for (int t = 0; t < nT; t++) {
    const int cur = t & 1;
    const u16* At = L[cur][0];
    const u16* Bt = L[cur][1];
    u16* Ax = L[cur ^ 1][0];
    u16* Bx = L[cur ^ 1][1];
    const int kn = (t + 1) * 64;
    const bool nl = (t + 1 < nT);
    bf16x8 aF[2][4], bF0[2][2], bF1[2][2];

    // ---- P0: Q(mh=0,nh=0); needs A-half0,B-half0; stages A-half0(t+1) ----
    if (nl) { __asm__ __volatile__("s_waitcnt vmcnt(4)" ::: "memory"); }
    else    { __asm__ __volatile__("s_waitcnt vmcnt(0)" ::: "memory"); }
    __asm__ __volatile__("s_barrier" ::: "memory");
#pragma unroll
    for (int kk = 0; kk < 2; kk++) {
#pragma unroll
      for (int mi = 0; mi < 4; mi++)
        aF[kk][mi] = *(const bf16x8*)&At[aRow[mi] * 64 + (((kk * 4 + quad) ^ (aRow[mi] & 7)) * 8)];
#pragma unroll
      for (int ni = 0; ni < 2; ni++)
        bF0[kk][ni] = *(const bf16x8*)&Bt[bRow[ni] * 64 + (((kk * 4 + quad) ^ (bRow[ni] & 7)) * 8)];
    }
    if (nl) stage_half(A, m0, kn, 0, Ax, tid);
    __asm__ __volatile__("s_waitcnt lgkmcnt(0)" ::: "memory");
    __builtin_amdgcn_sched_barrier(0);
    __builtin_amdgcn_s_setprio(1);
#pragma unroll
    for (int kk = 0; kk < 2; kk++)
#pragma unroll
      for (int mi = 0; mi < 4; mi++)
#pragma unroll
        for (int ni = 0; ni < 2; ni++)
          acc[mi][ni] = __builtin_amdgcn_mfma_f32_16x16x32_bf16(aF[kk][mi], bF0[kk][ni], acc[mi][ni], 0, 0, 0);
    __builtin_amdgcn_s_setprio(0);
    __builtin_amdgcn_sched_barrier(0);

    // ---- P1: Q(1,0); needs A-half1 (reuse bF0); stages B-half0(t+1) ----
    if (nl) { __asm__ __volatile__("s_waitcnt vmcnt(4)" ::: "memory"); }
    __asm__ __volatile__("s_barrier" ::: "memory");
#pragma unroll
    for (int kk = 0; kk < 2; kk++)
#pragma unroll
      for (int mi = 0; mi < 4; mi++)
        aF[kk][mi] = *(const bf16x8*)&At[aRow[4 + mi] * 64 + (((kk * 4 + quad) ^ (aRow[4 + mi] & 7)) * 8)];
    if (nl) stage_half(Bm, n0, kn, 0, Bx, tid);
    __asm__ __volatile__("s_waitcnt lgkmcnt(0)" ::: "memory");
    __builtin_amdgcn_sched_barrier(0);
    __builtin_amdgcn_s_setprio(1);
#pragma unroll
    for (int kk = 0; kk < 2; kk++)
#pragma unroll
      for (int mi = 0; mi < 4; mi++)
#pragma unroll
        for (int ni = 0; ni < 2; ni++)
          acc[4 + mi][ni] = __builtin_amdgcn_mfma_f32_16x16x32_bf16(aF[kk][mi], bF0[kk][ni], acc[4 + mi][ni], 0, 0, 0);
    __builtin_amdgcn_s_setprio(0);
    __builtin_amdgcn_sched_barrier(0);

    // ---- P2: Q(1,1); needs B-half1 (reuse aF=A1); stages A-half1(t+1) ----
    if (nl) { __asm__ __volatile__("s_waitcnt vmcnt(4)" ::: "memory"); }
    __asm__ __volatile__("s_barrier" ::: "memory");
#pragma unroll
    for (int kk = 0; kk < 2; kk++)
#pragma unroll
      for (int ni = 0; ni < 2; ni++)
        bF1[kk][ni] = *(const bf16x8*)&Bt[bRow[2 + ni] * 64 + (((kk * 4 + quad) ^ (bRow[2 + ni] & 7)) * 8)];
    if (nl) stage_half(A, m0, kn, 1, Ax, tid);
    __asm__ __volatile__("s_waitcnt lgkmcnt(0)" ::: "memory");
    __builtin_amdgcn_sched_barrier(0);
    __builtin_amdgcn_s_setprio(1);
#pragma unroll
    for (int kk = 0; kk < 2; kk++)
#pragma unroll
      for (int mi = 0; mi < 4; mi++)
#pragma unroll
        for (int ni = 0; ni < 2; ni++)
          acc[4 + mi][2 + ni] = __builtin_amdgcn_mfma_f32_16x16x32_bf16(aF[kk][mi], bF1[kk][ni], acc[4 + mi][2 + ni], 0, 0, 0);
    __builtin_amdgcn_s_setprio(0);
    __builtin_amdgcn_sched_barrier(0);

    // ---- P3: Q(0,1); re-reads A-half0 (reuse bF1); stages B-half1(t+1) ----
    // No vmcnt/barrier: reads data already validated at P0; the cross-tile
    // overwrite of this region is fenced by next tile's P0 vmcnt+barrier.
#pragma unroll
    for (int kk = 0; kk < 2; kk++)
#pragma unroll
      for (int mi = 0; mi < 4; mi++)
        aF[kk][mi] = *(const bf16x8*)&At[aRow[mi] * 64 + (((kk * 4 + quad) ^ (aRow[mi] & 7)) * 8)];
    if (nl) stage_half(Bm, n0, kn, 1, Bx, tid);
    __asm__ __volatile__("s_waitcnt lgkmcnt(0)" ::: "memory");
    __builtin_amdgcn_sched_barrier(0);
    __builtin_amdgcn_s_setprio(1);
#pragma unroll
    for (int kk = 0; kk < 2; kk++)
#pragma unroll
      for (int mi = 0; mi < 4; mi++)
#pragma unroll
        for (int ni = 0; ni < 2; ni++)
          acc[mi][2 + ni] = __builtin_amdgcn_mfma_f32_16x16x32_bf16(aF[kk][mi], bF1[kk][ni], acc[mi][2 + ni], 0, 0, 0);
    __builtin_amdgcn_s_setprio(0);
    __builtin_amdgcn_sched_barrier(0);
  }

  // ---------------- epilogue ----------------
  const int tensor = n0 >> 11;          // 0:q 1:k 2:v
  const int nloc0 = n0 & 2047;          // tensor-local col base
  if (tensor < 2) {
    u16* dst = (tensor == 0) ? qo : ko;
#pragma unroll
    for (int mi = 0; mi < 8; mi++) {
      int rowM = (mi < 4) ? (wm * 64 + mi * 16) : (128 + wm * 64 + (mi - 4) * 16);
#pragma unroll
      for (int r = 0; r < 4; r++) {
        int m = m0 + rowM + quad * 4 + r;
        int b = m >> 11, s = m & 2047;
        const float* fr = fct + s * 128;
#pragma unroll
        for (int ni = 0; ni < 4; ni++) {
          int colN = ((ni < 2) ? (wn * 32 + ni * 16) : (128 + wn * 32 + (ni - 2) * 16)) + ln;
          int h = (nloc0 + colN) >> 7;
          int j = colN & 127;
          dst[((size_t)(b * NH + h) * SS + s) * HD + j] = f2bf(acc[mi][ni][r] * fr[j]);
        }
      }
    }
  } else {
    // V: transpose 256(s) x 256(hd-cols spanning 2 heads) via LDS, then
    // coalesced 16B stores to (B,NH,HD,S).
    __syncthreads();                    // everyone done reading L
    u16* Tr = (u16*)L;                  // 128KB = 256 hd-rows x 256 s-cols
    const int b = m0 >> 11, s0 = m0 & 2047;
#pragma unroll
    for (int mi = 0; mi < 8; mi++) {
      int rowM = (mi < 4) ? (wm * 64 + mi * 16) : (128 + wm * 64 + (mi - 4) * 16);
#pragma unroll
      for (int ni = 0; ni < 4; ni++) {
        int colN = ((ni < 2) ? (wn * 32 + ni * 16) : (128 + wn * 32 + (ni - 2) * 16)) + ln;
#pragma unroll
        for (int r = 0; r < 4; r++) {
          int srel = rowM + quad * 4 + r;
          int ch = srel >> 3;
          Tr[colN * 256 + ((ch ^ (colN & 31)) * 8) + (srel & 7)] = f2bf(acc[mi][ni][r]);
        }
      }
    }
    __syncthreads();
#pragma unroll
    for (int it = 0; it < 16; it++) {
      int slot = it * 512 + tid;
      int nloc = slot >> 5, c8 = slot & 31;
      uint4 val = *(const uint4*)&Tr[nloc * 256 + ((c8 ^ (nloc & 31)) * 8)];
      int h = (nloc0 >> 7) + (nloc >> 7);
      int hd = nloc & 127;
      *(uint4*)(vo + ((size_t)(b * NH + h) * HD + hd) * SS + s0 + c8 * 8) = val;
    }
  }
}

// ---------------- Flash attention v4 ----------------
// grid (16, NH, B) = 512 blocks, 2 blocks/CU (LDS 72KB, launch_bounds(256,2)).
// Block bx handles 64-row q-tiles {bx, 31-bx} -> uniform 33 k-tile units/block.
// Q loaded direct global->registers (no LDS staging). K/V double-buffered,
// XOR-swizzled LDS for conflict-free ds_read_b128. P buffer 8KB, wave-private.
__global__ __launch_bounds__(256, 2)
void flash_attn(const u16* __restrict__ q, const u16* __restrict__ k,
                const u16* __restrict__ v, u16* __restrict__ o) {
  __shared__ __align__(16) u16 Ps[64 * 64];       // 8KB: P (wave-private 16-row slabs)
  __shared__ __align__(16) u16 Ks[2][64 * 128];   // 2 x 16KB
  __shared__ __align__(16) u16 Vs[2][128 * 64];   // 2 x 16KB (Vt: hd rows, k cols)
  const int tid = threadIdx.x;
  const int w = tid >> 6, lane = tid & 63, ln = lane & 15, quad = lane >> 4;
  const int hh = blockIdx.y, b = blockIdx.z;
  const size_t bh = (size_t)b * NH + hh;
  const u16* Kg = k + bh * SS * HD;
  const u16* Vg = v + bh * HD * SS;

  for (int half = 0; half < 2; half++) {
    const int T = half ? (31 - (int)blockIdx.x) : (int)blockIdx.x;
    const u16* Qg = q + bh * SS * HD + (size_t)T * 64 * HD;

    // Q -> registers, direct from global (read once; 4 x 16B/lane)
    bf16x8 qf[4];
#pragma unroll
    for (int kc = 0; kc < 4; kc++)
      qf[kc] = *(const bf16x8*)(Qg + (size_t)(w * 16 + ln) * HD + (kc * 4 + quad) * 8);

    __syncthreads();   // Ks/Vs free of previous tile's readers

    // prefetch kt=0 into buffer 0
#pragma unroll
    for (int i = 0; i < 4; i++) {
      int slot = i * 256 + tid;
      int r = slot >> 4, c = (slot & 15) ^ (r & 7);
      load_lds16(Kg + (size_t)r * HD + c * 8, (char*)Ks[0] + slot * 16);
    }
#pragma unroll
    for (int i = 0; i < 4; i++) {
      int slot = i * 256 + tid;
      int r = slot >> 3, c = (slot & 7) ^ (r & 7);
      load_lds16(Vg + (size_t)r * SS + c * 8, (char*)Vs[0] + slot * 16);
    }

    const f32x4 fz = {0.f, 0.f, 0.f, 0.f};
    float m_s[4], l_s[4];
    f32x4 accO[8];
#pragma unroll
    for (int r = 0; r < 4; r++) { m_s[r] = -1e30f; l_s[r] = 0.f; }
#pragma unroll
    for (int nt = 0; nt < 8; nt++) accO[nt] = fz;

    const int nkt = T + 1;
    const int qrb = T * 64 + w * 16;

    for (int kt = 0; kt < nkt; kt++) {
      const int cur = kt & 1;
      const int k0 = kt * 64;
      // drain the staging issued one iteration ago (latency already hidden)
      __asm__ __volatile__("s_waitcnt vmcnt(0)" ::: "memory");
      __syncthreads();
      if (kt + 1 < nkt) {   // prefetch next k-tile into the other buffer
        const int kn = k0 + 64;
#pragma unroll
        for (int i = 0; i < 4; i++) {
          int slot = i * 256 + tid;
          int r = slot >> 4, c = (slot & 15) ^ (r & 7);
          load_lds16(Kg + (size_t)(kn + r) * HD + c * 8, (char*)Ks[cur ^ 1] + slot * 16);
        }
#pragma unroll
        for (int i = 0; i < 4; i++) {
          int slot = i * 256 + tid;
          int r = slot >> 3, c = (slot & 7) ^ (r & 7);
          load_lds16(Vg + (size_t)r * SS + kn + c * 8, (char*)Vs[cur ^ 1] + slot * 16);
        }
      }

      // S = Q K^T  (16 q-rows x 64 k-cols per wave)
      f32x4 sc[4];
#pragma unroll
      for (int nt = 0; nt < 4; nt++) sc[nt] = fz;
#pragma unroll
      for (int kc = 0; kc < 4; kc++)
#pragma unroll
        for (int nt = 0; nt < 4; nt++) {
          bf16x8 bf = *(const bf16x8*)&Ks[cur][(nt * 16 + ln) * 128 + (((kc * 4 + quad) ^ (ln & 7)) * 8)];
          sc[nt] = __builtin_amdgcn_mfma_f32_16x16x32_bf16(qf[kc], bf, sc[nt], 0, 0, 0);
        }

      const bool partial = (kt == T);
#pragma unroll
      for (int nt = 0; nt < 4; nt++)
#pragma unroll
        for (int r = 0; r < 4; r++) {
          float val = sc[nt][r] * SCALE;
          if (partial && (k0 + nt * 16 + ln > qrb + quad * 4 + r)) val = -1e9f;
          sc[nt][r] = val;
        }

      // online softmax per row
#pragma unroll
      for (int r = 0; r < 4; r++) {
        float mx = fmaxf(fmaxf(sc[0][r], sc[1][r]), fmaxf(sc[2][r], sc[3][r]));
#pragma unroll
        for (int off = 1; off < 16; off <<= 1) mx = fmaxf(mx, __shfl_xor(mx, off));
        float mnew = fmaxf(m_s[r], mx);
        float alpha = exp2f((m_s[r] - mnew) * LOG2E);
        float rs = 0.f;
#pragma unroll
        for (int nt = 0; nt < 4; nt++) {
          float p = exp2f((sc[nt][r] - mnew) * LOG2E);
          sc[nt][r] = p;
          rs += p;
        }
#pragma unroll
        for (int off = 1; off < 16; off <<= 1) rs += __shfl_xor(rs, off);
        l_s[r] = l_s[r] * alpha + rs;
        m_s[r] = mnew;
#pragma unroll
        for (int nt = 0; nt < 8; nt++) accO[nt][r] *= alpha;
      }

      // P: C-layout -> LDS (swizzled, wave-private 16-row slab) -> A-layout
#pragma unroll
      for (int nt = 0; nt < 4; nt++)
#pragma unroll
        for (int r = 0; r < 4; r++) {
          int rr = w * 16 + quad * 4 + r;
          int j = nt * 16 + ln;
          Ps[rr * 64 + (((j >> 3) ^ (rr & 7)) * 8) + (j & 7)] = f2bf(sc[nt][r]);
        }
      __asm__ __volatile__("s_waitcnt lgkmcnt(0)" ::: "memory");

      bf16x8 pf[2];
#pragma unroll
      for (int kc = 0; kc < 2; kc++) {
        int rp = w * 16 + ln;
        pf[kc] = *(const bf16x8*)&Ps[rp * 64 + (((kc * 4 + quad) ^ (ln & 7)) * 8)];
      }

      // O += P V
#pragma unroll
      for (int kc = 0; kc < 2; kc++)
#pragma unroll
        for (int nt = 0; nt < 8; nt++) {
          bf16x8 vf = *(const bf16x8*)&Vs[cur][(nt * 16 + ln) * 64 + (((kc * 4 + quad) ^ (ln & 7)) * 8)];
          accO[nt] = __builtin_amdgcn_mfma_f32_16x16x32_bf16(pf[kc], vf, accO[nt], 0, 0, 0);
        }
    }

    // normalize + store (B, S, DM) bf16
#pragma unroll
    for (int r = 0; r < 4; r++) {
      float ilv = 1.f / l_s[r];
      int srow = T * 64 + w * 16 + quad * 4 + r;
      size_t base = ((size_t)b * SS + srow) * DM + hh * HD;
#pragma unroll
      for (int nt = 0; nt < 8; nt++)
        o[base + nt * 16 + ln] = f2bf(accO[nt][r] * ilv);
    }
  }
}

// ---------------- Output GEMM (M=4096, N=2048, K=2048), fp32 epilogue --------
__global__ __launch_bounds__(256, 2)
void gemm_out(const u16* __restrict__ A, const u16* __restrict__ Bm,
              float* __restrict__ C) {
  __shared__ __align__(16) u16 As[128 * 32];
  __shared__ __align__(16) u16 Bs[128 * 32];
  const int tid = threadIdx.x;
  const int w = tid >> 6, lane = tid & 63, ln = lane & 15, quad = lane >> 4;
  const int m0 = blockIdx.x * 128, n0 = blockIdx.y * 128;

  const f32x4 fz = {0.f, 0.f, 0.f, 0.f};
  f32x4 acc[2][8];
#pragma unroll
  for (int mt = 0; mt < 2; mt++)
#pragma unroll
    for (int nt = 0; nt < 8; nt++) acc[mt][nt] = fz;

  for (int k0 = 0; k0 < KK; k0 += 32) {
    __syncthreads();
#pragma unroll
    for (int i = 0; i < 2; i++) {
      int tt = i * 256 + tid;
      load_lds16(A + (size_t)(m0 + (tt >> 2)) * KK + k0 + (tt & 3) * 8, (char*)As + tt * 16);
    }
#pragma unroll
    for (int i = 0; i < 2; i++) {
      int tt = i * 256 + tid;
      load_lds16(Bm + (size_t)(n0 + (tt >> 2)) * KK + k0 + (tt & 3) * 8, (char*)Bs + tt * 16);
    }
    __syncthreads();
    bf16x8 af[2];
#pragma unroll
    for (int mt = 0; mt < 2; mt++)
      af[mt] = *(const bf16x8*)&As[(w * 32 + mt * 16 + ln) * 32 + quad * 8];
#pragma unroll
    for (int nt = 0; nt < 8; nt++) {
      bf16x8 bf = *(const bf16x8*)&Bs[(nt * 16 + ln) * 32 + quad * 8];
#pragma unroll
      for (int mt = 0; mt < 2; mt++)
        acc[mt][nt] = __builtin_amdgcn_mfma_f32_16x16x32_bf16(af[mt], bf, acc[mt][nt], 0, 0, 0);
    }
  }

#pragma unroll
  for (int mt = 0; mt < 2; mt++)
#pragma unroll
    for (int r = 0; r < 4; r++) {
      int m = m0 + w * 32 + mt * 16 + quad * 4 + r;
#pragma unroll
      for (int nt = 0; nt < 8; nt++)
        C[(size_t)m * DM + n0 + nt * 16 + ln] = acc[mt][nt][r];
    }
}

// ---------------- launch ----------------
extern "C" void kernel_launch(void* const* d_in, const int* in_sizes, int n_in,
                              void* d_out, int out_size, void* d_ws, size_t ws_size,
                              hipStream_t stream) {
  (void)in_sizes; (void)n_in; (void)out_size; (void)ws_size;
  const float* x  = (const float*)d_in[0];
  // d_in[1] = attention_mask (exact causal tril) — implemented analytically
  const float* Wq = (const float*)d_in[2];
  const float* Wk = (const float*)d_in[3];
  const float* Wv = (const float*)d_in[4];
  const float* Wd = (const float*)d_in[5];

  // Workspace (96 MiB):
  //   [0,16M) xb (reused as aob)  [16M,40M) wqkv  [40M..] fct then wdb
  //   [48M,64M) qb  [64M,80M) kb  [80M,96M) vtb
  char* ws = (char*)d_ws;
  u16* xb   = (u16*)(ws);
  u16* aob  = xb;
  u16* wqkv = (u16*)(ws + 16777216ull);
  float* fct = (float*)(ws + 41943040ull);
  u16* wdb  = (u16*)(ws + 41943040ull);
  u16* qb   = (u16*)(ws + 50331648ull);
  u16* kb   = (u16*)(ws + 67108864ull);
  u16* vtb  = (u16*)(ws + 83886080ull);

  cast_f32_bf16<<<8192, 256, 0, stream>>>(x,  xb, MM * KK);
  cast_f32_bf16<<<4096, 256, 0, stream>>>(Wq, wqkv,                   DM * KK);
  cast_f32_bf16<<<4096, 256, 0, stream>>>(Wk, wqkv + (size_t)DM*KK,   DM * KK);
  cast_f32_bf16<<<4096, 256, 0, stream>>>(Wv, wqkv + (size_t)2*DM*KK, DM * KK);
  rope_fct<<<1024, 256, 0, stream>>>(fct);

  gemm_qkv_rope<<<dim3(MM / 256, NQKV / 256), 512, 0, stream>>>(xb, wqkv, qb, kb, vtb, fct);

  cast_f32_bf16<<<4096, 256, 0, stream>>>(Wd, wdb, DM * KK);   // overwrites fct (dead)

  flash_attn<<<dim3(16, NH, BB), 256, 0, stream>>>(qb, kb, vtb, aob);
  gemm_out<<<dim3(MM / 128, DM / 128), 256, 0, stream>>>(aob, wdb, (float*)d_out);
}

// Round 3
// 400.925 us; speedup vs baseline: 1.2392x; 1.0201x over previous
//
#include <hip/hip_runtime.h>
#include <stdint.h>

// Problem constants
#define DM   2048
#define NH   16
#define HD   128
#define BB   2
#define SS   2048
#define MM   (BB*SS)     // 4096
#define KK   2048
#define NQKV (3*DM)      // 6144

#define LOG2E  1.4426950408889634f
#define SCALE  0.08838834764831845f   // 1/sqrt(128)

using bf16x8 = __attribute__((ext_vector_type(8))) __bf16;
using f32x4  = __attribute__((ext_vector_type(4))) float;
typedef unsigned short u16;
typedef unsigned int   u32;

__device__ __forceinline__ u16 f2bf(float f) {
  u32 u = __float_as_uint(f);
  u32 r = (u + 0x7FFFu + ((u >> 16) & 1u)) >> 16;   // RNE
  return (u16)r;
}

// async global->LDS, 16B per lane. LDS dest must be lane-contiguous (base+tid*16).
__device__ __forceinline__ void load_lds16(const void* g, void* l) {
  __builtin_amdgcn_global_load_lds(
      (__attribute__((address_space(1))) void*)(g),
      (__attribute__((address_space(3))) void*)(l), 16, 0, 0);
}

// ---------------- cast fp32 -> bf16 (4 elems/thread) ----------------
__global__ void cast_f32_bf16(const float* __restrict__ s, u16* __restrict__ d, int n) {
  int i = (blockIdx.x * blockDim.x + threadIdx.x) * 4;
  if (i < n) {
    float4 f = *(const float4*)(s + i);
    u32 lo = (u32)f2bf(f.x) | ((u32)f2bf(f.y) << 16);
    u32 hi = (u32)f2bf(f.z) | ((u32)f2bf(f.w) << 16);
    *(uint2*)(d + i) = make_uint2(lo, hi);
  }
}

// ---------------- "RoPE" factor table ----------------
// Reference's _rotate_half is the identity (splits 128-dim head at 128).
// q <- q*(cos+sin) elementwise. f[s][j] = cos(s*inv[j&63]) + sin(s*inv[j&63]).
__global__ void rope_fct(float* __restrict__ f) {
  int i = blockIdx.x * blockDim.x + threadIdx.x;   // SS*128 threads
  if (i < SS * 128) {
    int s = i >> 7, j = i & 127;
    double inv = pow(10000.0, -(double)(j & 63) / 64.0);
    float ang = (float)s * (float)inv;
    float sn, cs;
    sincosf(ang, &sn, &cs);
    f[i] = cs + sn;
  }
}

// ============ shared GEMM pattern: 256(M)x128(N) tile, BK=64 ============
// 512 threads = 8 waves (2M x 4N). Wave tile 128x32, M-rows interleaved
// across A-halves: mi<4 -> rows wm*64+mi*16 (A-half0), mi>=4 -> 128+wm*64+...
// (A-half1). So phase P0 reads only A-half0 (+all of B), P1 only A-half1.
// Stage units per K-tile (2 gload_lds/thread each), issue order: B, A0, A1.
// Counted vmcnt(2): at P0(t) outstanding={A1(t)},{next B not yet} -> oldest
// done = B(t),A0(t); at P1(t) outstanding={A1(t),B(t+1)} -> vmcnt(2) drains
// A1(t). Final tile P1 uses vmcnt(0). Buffer buf[t&1]; stages target
// buf[(t+1)&1], whose previous readers all drained before P0(t)'s barrier.
// LDS 96KB = bufA 2x32KB + bufB 2x16KB. Chunk-XOR swizzle (c^(r&7)) applied
// by pre-swizzling the global source (gload_lds dest must stay linear).

__device__ __forceinline__ void stage_unit(const u16* __restrict__ G, int rowbase,
                                           int kbase, u16* lds, int tid) {
#pragma unroll
  for (int i = 0; i < 2; i++) {
    int s = i * 512 + tid;
    int r = s >> 3, c = s & 7;
    load_lds16(G + (size_t)(rowbase + r) * KK + kbase + ((c ^ (r & 7)) * 8),
               (char*)lds + (size_t)s * 16);
  }
}

#define GEMM_MAIN_LOOP(EXTRA_LAST)                                              \
  const int tid = threadIdx.x;                                                  \
  const int wid = tid >> 6, lane = tid & 63, ln = lane & 15, quad = lane >> 4;  \
  const int wm = wid >> 2, wn = wid & 3;                                        \
  const int m0 = blockIdx.x * 256, n0 = blockIdx.y * 128;                       \
  const f32x4 fz = {0.f, 0.f, 0.f, 0.f};                                        \
  f32x4 acc[8][2];                                                              \
  _Pragma("unroll") for (int mi = 0; mi < 8; mi++)                              \
    _Pragma("unroll") for (int ni = 0; ni < 2; ni++) acc[mi][ni] = fz;          \
  int aRow[8], bRow[2];                                                         \
  _Pragma("unroll") for (int mi = 0; mi < 8; mi++)                              \
    aRow[mi] = ((mi < 4) ? (wm * 64 + mi * 16)                                  \
                         : (128 + wm * 64 + (mi - 4) * 16)) + ln;               \
  _Pragma("unroll") for (int ni = 0; ni < 2; ni++)                              \
    bRow[ni] = wn * 32 + ni * 16 + ln;                                          \
  /* prologue: stage tile 0 into buf 0: order B, A0, A1 */                      \
  stage_unit(Bm, n0, 0, LB[0], tid);                                            \
  stage_unit(A, m0, 0, LA[0], tid);                                             \
  stage_unit(A, m0 + 128, 0, LA[0] + 128 * 64, tid);                            \
  const int nT = KK / 64;                                                       \
  for (int t = 0; t < nT; t++) {                                                \
    const int cur = t & 1;                                                      \
    const u16* At = LA[cur];                                                    \
    const u16* Bt = LB[cur];                                                    \
    u16* Ax = LA[cur ^ 1];                                                      \
    u16* Bx = LB[cur ^ 1];                                                      \
    const int kn = (t + 1) * 64;                                                \
    const bool nl = (t + 1 < nT);                                               \
    bf16x8 aF[2][4], bF[2][2];                                                  \
    /* ---- P0: mi 0-3 (A-half0) x all B ---- */                                \
    __asm__ __volatile__("s_waitcnt vmcnt(2)" ::: "memory");                    \
    __asm__ __volatile__("s_barrier" ::: "memory");                             \
    _Pragma("unroll") for (int kk = 0; kk < 2; kk++) {                          \
      _Pragma("unroll") for (int mi = 0; mi < 4; mi++)                          \
        aF[kk][mi] = *(const bf16x8*)&At[aRow[mi] * 64 +                        \
                      (((kk * 4 + quad) ^ (aRow[mi] & 7)) * 8)];                \
      _Pragma("unroll") for (int ni = 0; ni < 2; ni++)                          \
        bF[kk][ni] = *(const bf16x8*)&Bt[bRow[ni] * 64 +                        \
                      (((kk * 4 + quad) ^ (bRow[ni] & 7)) * 8)];                \
    }                                                                           \
    if (nl) stage_unit(Bm, n0, kn, Bx, tid);                                    \
    __asm__ __volatile__("s_waitcnt lgkmcnt(0)" ::: "memory");                  \
    __builtin_amdgcn_sched_barrier(0);                                          \
    __builtin_amdgcn_s_setprio(1);                                              \
    _Pragma("unroll") for (int kk = 0; kk < 2; kk++)                            \
      _Pragma("unroll") for (int mi = 0; mi < 4; mi++)                          \
        _Pragma("unroll") for (int ni = 0; ni < 2; ni++)                        \
          acc[mi][ni] = __builtin_amdgcn_mfma_f32_16x16x32_bf16(                \
              aF[kk][mi], bF[kk][ni], acc[mi][ni], 0, 0, 0);                    \
    __builtin_amdgcn_s_setprio(0);                                              \
    __builtin_amdgcn_sched_barrier(0);                                          \
    /* ---- P1: mi 4-7 (A-half1), reuse bF ---- */                              \
    if (nl) { __asm__ __volatile__("s_waitcnt vmcnt(2)" ::: "memory"); }        \
    else    { __asm__ __volatile__("s_waitcnt vmcnt(0)" ::: "memory"); }        \
    __asm__ __volatile__("s_barrier" ::: "memory");                             \
    _Pragma("unroll") for (int kk = 0; kk < 2; kk++)                            \
      _Pragma("unroll") for (int mi = 0; mi < 4; mi++)                          \
        aF[kk][mi] = *(const bf16x8*)&At[aRow[4 + mi] * 64 +                    \
                      (((kk * 4 + quad) ^ (aRow[4 + mi] & 7)) * 8)];            \
    if (nl) {                                                                   \
      stage_unit(A, m0, kn, Ax, tid);                                           \
      stage_unit(A, m0 + 128, kn, Ax + 128 * 64, tid);                          \
    }                                                                           \
    __asm__ __volatile__("s_waitcnt lgkmcnt(0)" ::: "memory");                  \
    __builtin_amdgcn_sched_barrier(0);                                          \
    __builtin_amdgcn_s_setprio(1);                                              \
    _Pragma("unroll") for (int kk = 0; kk < 2; kk++)                            \
      _Pragma("unroll") for (int mi = 0; mi < 4; mi++)                          \
        _Pragma("unroll") for (int ni = 0; ni < 2; ni++)                        \
          acc[4 + mi][ni] = __builtin_amdgcn_mfma_f32_16x16x32_bf16(            \
              aF[kk][mi], bF[kk][ni], acc[4 + mi][ni], 0, 0, 0);                \
    __builtin_amdgcn_s_setprio(0);                                              \
    __builtin_amdgcn_sched_barrier(0);                                          \
    (void)0; EXTRA_LAST                                                         \
  }

// ---------------- QKV GEMM (M=4096, N=6144, K=2048) + fused q/k scaling -----
// grid (16, 48) = 768 blocks = 3.0 exact dispatch rounds at 1 block/CU.
__global__ __launch_bounds__(512, 2)
void gemm_qkv_rope(const u16* __restrict__ A, const u16* __restrict__ Bm,
                   u16* __restrict__ qo, u16* __restrict__ ko, u16* __restrict__ vo,
                   const float* __restrict__ fct) {
  __shared__ __align__(16) u16 LA[2][256 * 64];   // 64 KB
  __shared__ __align__(16) u16 LB[2][128 * 64];   // 32 KB
  GEMM_MAIN_LOOP()

  // ---------------- epilogue ----------------
  const int tensor = n0 >> 11;          // 0:q 1:k 2:v (by: 0-15,16-31,32-47)
  const int h = (n0 & 2047) >> 7;       // whole block within ONE head
  if (tensor < 2) {
    u16* dst = (tensor == 0) ? qo : ko;
#pragma unroll
    for (int mi = 0; mi < 8; mi++) {
      int rowM = (mi < 4) ? (wm * 64 + mi * 16) : (128 + wm * 64 + (mi - 4) * 16);
#pragma unroll
      for (int r = 0; r < 4; r++) {
        int m = m0 + rowM + quad * 4 + r;
        int b = m >> 11, s = m & 2047;
        const float* fr = fct + s * 128;
#pragma unroll
        for (int ni = 0; ni < 2; ni++) {
          int j = wn * 32 + ni * 16 + ln;   // head-local col 0..127
          dst[((size_t)(b * NH + h) * SS + s) * HD + j] = f2bf(acc[mi][ni][r] * fr[j]);
        }
      }
    }
  } else {
    // V: transpose 256(s) x 128(hd) via LDS, coalesced 16B stores to (B,NH,HD,S)
    __syncthreads();                    // all waves done reading LA/LB
    u16* Tr = (u16*)LA;                 // 64KB = 128 hd-rows x 256 s-cols
    const int b = m0 >> 11, s0 = m0 & 2047;
#pragma unroll
    for (int mi = 0; mi < 8; mi++) {
      int rowM = (mi < 4) ? (wm * 64 + mi * 16) : (128 + wm * 64 + (mi - 4) * 16);
#pragma unroll
      for (int ni = 0; ni < 2; ni++) {
        int hd = wn * 32 + ni * 16 + ln;
#pragma unroll
        for (int r = 0; r < 4; r++) {
          int srel = rowM + quad * 4 + r;
          int ch = srel >> 3;
          Tr[hd * 256 + ((ch ^ (hd & 31)) * 8) + (srel & 7)] = f2bf(acc[mi][ni][r]);
        }
      }
    }
    __syncthreads();
#pragma unroll
    for (int it = 0; it < 8; it++) {
      int slot = it * 512 + tid;
      int hd = slot >> 5, c8 = slot & 31;
      uint4 val = *(const uint4*)&Tr[hd * 256 + ((c8 ^ (hd & 31)) * 8)];
      *(uint4*)(vo + ((size_t)(b * NH + h) * HD + hd) * SS + s0 + c8 * 8) = val;
    }
  }
}

// ---------------- Output GEMM (M=4096, N=2048, K=2048), fp32 epilogue --------
// grid (16, 16) = 256 blocks = 1.0 exact dispatch round at 1 block/CU.
__global__ __launch_bounds__(512, 2)
void gemm_out(const u16* __restrict__ A, const u16* __restrict__ Bm,
              float* __restrict__ C) {
  __shared__ __align__(16) u16 LA[2][256 * 64];   // 64 KB
  __shared__ __align__(16) u16 LB[2][128 * 64];   // 32 KB
  GEMM_MAIN_LOOP()

#pragma unroll
  for (int mi = 0; mi < 8; mi++) {
    int rowM = (mi < 4) ? (wm * 64 + mi * 16) : (128 + wm * 64 + (mi - 4) * 16);
#pragma unroll
    for (int r = 0; r < 4; r++) {
      int m = m0 + rowM + quad * 4 + r;
#pragma unroll
      for (int ni = 0; ni < 2; ni++)
        C[(size_t)m * DM + n0 + wn * 32 + ni * 16 + ln] = acc[mi][ni][r];
    }
  }
}

// ---------------- Flash attention v4 ----------------
// grid (16, NH, B) = 512 blocks, 2 blocks/CU (LDS 72KB, launch_bounds(256,2)).
// Block bx handles 64-row q-tiles {bx, 31-bx} -> uniform 33 k-tile units/block.
// Q loaded direct global->registers (no LDS staging). K/V double-buffered,
// XOR-swizzled LDS for conflict-free ds_read_b128. P buffer 8KB, wave-private.
__global__ __launch_bounds__(256, 2)
void flash_attn(const u16* __restrict__ q, const u16* __restrict__ k,
                const u16* __restrict__ v, u16* __restrict__ o) {
  __shared__ __align__(16) u16 Ps[64 * 64];       // 8KB: P (wave-private 16-row slabs)
  __shared__ __align__(16) u16 Ks[2][64 * 128];   // 2 x 16KB
  __shared__ __align__(16) u16 Vs[2][128 * 64];   // 2 x 16KB (Vt: hd rows, k cols)
  const int tid = threadIdx.x;
  const int w = tid >> 6, lane = tid & 63, ln = lane & 15, quad = lane >> 4;
  const int hh = blockIdx.y, b = blockIdx.z;
  const size_t bh = (size_t)b * NH + hh;
  const u16* Kg = k + bh * SS * HD;
  const u16* Vg = v + bh * HD * SS;

  for (int half = 0; half < 2; half++) {
    const int T = half ? (31 - (int)blockIdx.x) : (int)blockIdx.x;
    const u16* Qg = q + bh * SS * HD + (size_t)T * 64 * HD;

    // Q -> registers, direct from global (read once; 4 x 16B/lane)
    bf16x8 qf[4];
#pragma unroll
    for (int kc = 0; kc < 4; kc++)
      qf[kc] = *(const bf16x8*)(Qg + (size_t)(w * 16 + ln) * HD + (kc * 4 + quad) * 8);

    __syncthreads();   // Ks/Vs free of previous tile's readers

    // prefetch kt=0 into buffer 0
#pragma unroll
    for (int i = 0; i < 4; i++) {
      int slot = i * 256 + tid;
      int r = slot >> 4, c = (slot & 15) ^ (r & 7);
      load_lds16(Kg + (size_t)r * HD + c * 8, (char*)Ks[0] + slot * 16);
    }
#pragma unroll
    for (int i = 0; i < 4; i++) {
      int slot = i * 256 + tid;
      int r = slot >> 3, c = (slot & 7) ^ (r & 7);
      load_lds16(Vg + (size_t)r * SS + c * 8, (char*)Vs[0] + slot * 16);
    }

    const f32x4 fz = {0.f, 0.f, 0.f, 0.f};
    float m_s[4], l_s[4];
    f32x4 accO[8];
#pragma unroll
    for (int r = 0; r < 4; r++) { m_s[r] = -1e30f; l_s[r] = 0.f; }
#pragma unroll
    for (int nt = 0; nt < 8; nt++) accO[nt] = fz;

    const int nkt = T + 1;
    const int qrb = T * 64 + w * 16;

    for (int kt = 0; kt < nkt; kt++) {
      const int cur = kt & 1;
      const int k0 = kt * 64;
      // drain the staging issued one iteration ago (latency already hidden)
      __asm__ __volatile__("s_waitcnt vmcnt(0)" ::: "memory");
      __syncthreads();
      if (kt + 1 < nkt) {   // prefetch next k-tile into the other buffer
        const int kn = k0 + 64;
#pragma unroll
        for (int i = 0; i < 4; i++) {
          int slot = i * 256 + tid;
          int r = slot >> 4, c = (slot & 15) ^ (r & 7);
          load_lds16(Kg + (size_t)(kn + r) * HD + c * 8, (char*)Ks[cur ^ 1] + slot * 16);
        }
#pragma unroll
        for (int i = 0; i < 4; i++) {
          int slot = i * 256 + tid;
          int r = slot >> 3, c = (slot & 7) ^ (r & 7);
          load_lds16(Vg + (size_t)r * SS + kn + c * 8, (char*)Vs[cur ^ 1] + slot * 16);
        }
      }

      // S = Q K^T  (16 q-rows x 64 k-cols per wave)
      f32x4 sc[4];
#pragma unroll
      for (int nt = 0; nt < 4; nt++) sc[nt] = fz;
#pragma unroll
      for (int kc = 0; kc < 4; kc++)
#pragma unroll
        for (int nt = 0; nt < 4; nt++) {
          bf16x8 bf = *(const bf16x8*)&Ks[cur][(nt * 16 + ln) * 128 + (((kc * 4 + quad) ^ (ln & 7)) * 8)];
          sc[nt] = __builtin_amdgcn_mfma_f32_16x16x32_bf16(qf[kc], bf, sc[nt], 0, 0, 0);
        }

      const bool partial = (kt == T);
#pragma unroll
      for (int nt = 0; nt < 4; nt++)
#pragma unroll
        for (int r = 0; r < 4; r++) {
          float val = sc[nt][r] * SCALE;
          if (partial && (k0 + nt * 16 + ln > qrb + quad * 4 + r)) val = -1e9f;
          sc[nt][r] = val;
        }

      // online softmax per row
#pragma unroll
      for (int r = 0; r < 4; r++) {
        float mx = fmaxf(fmaxf(sc[0][r], sc[1][r]), fmaxf(sc[2][r], sc[3][r]));
#pragma unroll
        for (int off = 1; off < 16; off <<= 1) mx = fmaxf(mx, __shfl_xor(mx, off));
        float mnew = fmaxf(m_s[r], mx);
        float alpha = exp2f((m_s[r] - mnew) * LOG2E);
        float rs = 0.f;
#pragma unroll
        for (int nt = 0; nt < 4; nt++) {
          float p = exp2f((sc[nt][r] - mnew) * LOG2E);
          sc[nt][r] = p;
          rs += p;
        }
#pragma unroll
        for (int off = 1; off < 16; off <<= 1) rs += __shfl_xor(rs, off);
        l_s[r] = l_s[r] * alpha + rs;
        m_s[r] = mnew;
#pragma unroll
        for (int nt = 0; nt < 8; nt++) accO[nt][r] *= alpha;
      }

      // P: C-layout -> LDS (swizzled, wave-private 16-row slab) -> A-layout
#pragma unroll
      for (int nt = 0; nt < 4; nt++)
#pragma unroll
        for (int r = 0; r < 4; r++) {
          int rr = w * 16 + quad * 4 + r;
          int j = nt * 16 + ln;
          Ps[rr * 64 + (((j >> 3) ^ (rr & 7)) * 8) + (j & 7)] = f2bf(sc[nt][r]);
        }
      __asm__ __volatile__("s_waitcnt lgkmcnt(0)" ::: "memory");

      bf16x8 pf[2];
#pragma unroll
      for (int kc = 0; kc < 2; kc++) {
        int rp = w * 16 + ln;
        pf[kc] = *(const bf16x8*)&Ps[rp * 64 + (((kc * 4 + quad) ^ (ln & 7)) * 8)];
      }

      // O += P V
#pragma unroll
      for (int kc = 0; kc < 2; kc++)
#pragma unroll
        for (int nt = 0; nt < 8; nt++) {
          bf16x8 vf = *(const bf16x8*)&Vs[cur][(nt * 16 + ln) * 64 + (((kc * 4 + quad) ^ (ln & 7)) * 8)];
          accO[nt] = __builtin_amdgcn_mfma_f32_16x16x32_bf16(pf[kc], vf, accO[nt], 0, 0, 0);
        }
    }

    // normalize + store (B, S, DM) bf16
#pragma unroll
    for (int r = 0; r < 4; r++) {
      float ilv = 1.f / l_s[r];
      int srow = T * 64 + w * 16 + quad * 4 + r;
      size_t base = ((size_t)b * SS + srow) * DM + hh * HD;
#pragma unroll
      for (int nt = 0; nt < 8; nt++)
        o[base + nt * 16 + ln] = f2bf(accO[nt][r] * ilv);
    }
  }
}

// ---------------- launch ----------------
extern "C" void kernel_launch(void* const* d_in, const int* in_sizes, int n_in,
                              void* d_out, int out_size, void* d_ws, size_t ws_size,
                              hipStream_t stream) {
  (void)in_sizes; (void)n_in; (void)out_size; (void)ws_size;
  const float* x  = (const float*)d_in[0];
  // d_in[1] = attention_mask (exact causal tril) — implemented analytically
  const float* Wq = (const float*)d_in[2];
  const float* Wk = (const float*)d_in[3];
  const float* Wv = (const float*)d_in[4];
  const float* Wd = (const float*)d_in[5];

  // Workspace (96 MiB):
  //   [0,16M) xb (reused as aob)  [16M,40M) wqkv  [40M..] fct then wdb
  //   [48M,64M) qb  [64M,80M) kb  [80M,96M) vtb
  char* ws = (char*)d_ws;
  u16* xb   = (u16*)(ws);
  u16* aob  = xb;
  u16* wqkv = (u16*)(ws + 16777216ull);
  float* fct = (float*)(ws + 41943040ull);
  u16* wdb  = (u16*)(ws + 41943040ull);
  u16* qb   = (u16*)(ws + 50331648ull);
  u16* kb   = (u16*)(ws + 67108864ull);
  u16* vtb  = (u16*)(ws + 83886080ull);

  cast_f32_bf16<<<8192, 256, 0, stream>>>(x,  xb, MM * KK);
  cast_f32_bf16<<<4096, 256, 0, stream>>>(Wq, wqkv,                   DM * KK);
  cast_f32_bf16<<<4096, 256, 0, stream>>>(Wk, wqkv + (size_t)DM*KK,   DM * KK);
  cast_f32_bf16<<<4096, 256, 0, stream>>>(Wv, wqkv + (size_t)2*DM*KK, DM * KK);
  rope_fct<<<1024, 256, 0, stream>>>(fct);

  gemm_qkv_rope<<<dim3(MM / 256, NQKV / 128), 512, 0, stream>>>(xb, wqkv, qb, kb, vtb, fct);

  cast_f32_bf16<<<4096, 256, 0, stream>>>(Wd, wdb, DM * KK);   // overwrites fct (dead)

  flash_attn<<<dim3(16, NH, BB), 256, 0, stream>>>(qb, kb, vtb, aob);
  gemm_out<<<dim3(MM / 256, DM / 128), 512, 0, stream>>>(aob, wdb, (float*)d_out);
}

// Round 6
// 390.959 us; speedup vs baseline: 1.2707x; 1.0255x over previous
//
#include <hip/hip_runtime.h>
#include <stdint.h>

// Problem constants
#define DM   2048
#define NH   16
#define HD   128
#define BB   2
#define SS   2048
#define MM   (BB*SS)     // 4096
#define KK   2048
#define NQKV (3*DM)      // 6144

#define LOG2E  1.4426950408889634f
#define SCALE  0.08838834764831845f   // 1/sqrt(128)

using bf16x8 = __attribute__((ext_vector_type(8))) __bf16;
using f32x4  = __attribute__((ext_vector_type(4))) float;
typedef unsigned short u16;
typedef unsigned int   u32;

__device__ __forceinline__ u16 f2bf(float f) {
  u32 u = __float_as_uint(f);
  u32 r = (u + 0x7FFFu + ((u >> 16) & 1u)) >> 16;   // RNE
  return (u16)r;
}

// async global->LDS, 16B per lane. LDS dest must be lane-contiguous (base+tid*16).
__device__ __forceinline__ void load_lds16(const void* g, void* l) {
  __builtin_amdgcn_global_load_lds(
      (__attribute__((address_space(1))) void*)(g),
      (__attribute__((address_space(3))) void*)(l), 16, 0, 0);
}

// ---------------- cast fp32 -> bf16 (4 elems/thread) ----------------
__global__ void cast_f32_bf16(const float* __restrict__ s, u16* __restrict__ d, int n) {
  int i = (blockIdx.x * blockDim.x + threadIdx.x) * 4;
  if (i < n) {
    float4 f = *(const float4*)(s + i);
    u32 lo = (u32)f2bf(f.x) | ((u32)f2bf(f.y) << 16);
    u32 hi = (u32)f2bf(f.z) | ((u32)f2bf(f.w) << 16);
    *(uint2*)(d + i) = make_uint2(lo, hi);
  }
}

// ---------------- "RoPE" factor table ----------------
// Reference's _rotate_half is the identity (splits 128-dim head at 128).
// q <- q*(cos+sin) elementwise. f[s][j] = cos(s*inv[j&63]) + sin(s*inv[j&63]).
__global__ void rope_fct(float* __restrict__ f) {
  int i = blockIdx.x * blockDim.x + threadIdx.x;   // SS*128 threads
  if (i < SS * 128) {
    int s = i >> 7, j = i & 127;
    double inv = pow(10000.0, -(double)(j & 63) / 64.0);
    float ang = (float)s * (float)inv;
    float sn, cs;
    sincosf(ang, &sn, &cs);
    f[i] = cs + sn;
  }
}

// ============ shared GEMM pattern: 128(M) x 256(N) tile, BK=64 ============
// 512 threads = 8 waves (2M x 4N), wave tile 64x64 -> 2.0 MFMA per ds_read_b128.
// Wave N-cols INTERLEAVED across B-halves: ni 0,1 -> wn*32+{0,16} (B-half0,
// read at P0); ni 2,3 -> 128+wn*32+{0,16} (B-half1, read at P1). This keeps
// the phase<->half invariant the vmcnt ledger needs (round-5 bug: contiguous
// wn*64 cols made waves wn>=2 read B-half1 at P0 while its loads were still
// in flight).
// Per K-tile, 2 phases:
//   P0: vmcnt(2); barrier; ds_read aF[2][4]+bF(ni0,1) (12 reads);
//       stage A(t+1)+Bhalf0(t+1) (4 loads); lgkmcnt(0); 16 MFMA (ni 0-1).
//   P1: vmcnt(4); barrier; ds_read bF(ni2,3) (4 reads);
//       stage Bhalf1(t+1) (2 loads); lgkmcnt(0); 16 MFMA (ni 2-3).
// vmcnt ledger (6 loads/tile, order A,B0 | B1): P0(t) needs {A(t),B0(t)} = the
// 4 oldest, leaves Bh1(t) (2 newest) in flight -> vmcnt(2). P1(t) needs Bh1(t);
// outstanding = Bh1(t)+4 just issued -> vmcnt(4). Last tile: vmcnt(2)/vmcnt(0).
// LDS 96KB layout (bytes): [0,16K)=LA buf0, [16K,32K)=LA buf1,
// [32K,64K)=LB buf0, [64K,96K)=LB buf1. Chunk-XOR swizzle c^(r&7) applied
// by pre-swizzling the global source (gload_lds dest stays linear).

__device__ __forceinline__ void stage_unit(const u16* __restrict__ G, int rowbase,
                                           int kbase, u16* lds, int tid) {
#pragma unroll
  for (int i = 0; i < 2; i++) {
    int s = i * 512 + tid;
    int r = s >> 3, c = s & 7;
    load_lds16(G + (size_t)(rowbase + r) * KK + kbase + ((c ^ (r & 7)) * 8),
               (char*)lds + (size_t)s * 16);
  }
}

#define COLN(ni) (((ni) < 2) ? (wn * 32 + (ni) * 16) : (128 + wn * 32 + ((ni) - 2) * 16))

#define GEMM_MAIN_LOOP                                                          \
  const int tid = threadIdx.x;                                                  \
  const int wid = tid >> 6, lane = tid & 63, ln = lane & 15, quad = lane >> 4;  \
  const int wm = wid >> 2, wn = wid & 3;                                        \
  const int m0 = blockIdx.x * 128, n0 = blockIdx.y * 256;                       \
  const f32x4 fz = {0.f, 0.f, 0.f, 0.f};                                        \
  f32x4 acc[4][4];                                                              \
  _Pragma("unroll") for (int mi = 0; mi < 4; mi++)                              \
    _Pragma("unroll") for (int ni = 0; ni < 4; ni++) acc[mi][ni] = fz;          \
  int aRow[4], bRow[4];                                                         \
  _Pragma("unroll") for (int mi = 0; mi < 4; mi++)                              \
    aRow[mi] = wm * 64 + mi * 16 + ln;                                          \
  _Pragma("unroll") for (int ni = 0; ni < 4; ni++)                              \
    bRow[ni] = COLN(ni) + ln;                                                   \
  /* prologue: tile 0 into buf 0, order A, Bh0, Bh1 */                          \
  stage_unit(A, m0, 0, Sh, tid);                                                \
  stage_unit(Bm, n0, 0, Sh + 16384, tid);                                       \
  stage_unit(Bm, n0 + 128, 0, Sh + 16384 + 8192, tid);                          \
  const int nT = KK / 64;                                                       \
  for (int t = 0; t < nT; t++) {                                                \
    const int cur = t & 1;                                                      \
    const u16* At = Sh + cur * 8192;                                            \
    const u16* Bt = Sh + 16384 + cur * 16384;                                   \
    u16* Ax = Sh + (cur ^ 1) * 8192;                                            \
    u16* Bx = Sh + 16384 + (cur ^ 1) * 16384;                                   \
    const int kn = (t + 1) * 64;                                                \
    const bool nl = (t + 1 < nT);                                               \
    bf16x8 aF[2][4], bF[2][2];                                                  \
    /* ---- P0: all mi x ni 0-1 (B-half0 only) ---- */                          \
    __asm__ __volatile__("s_waitcnt vmcnt(2)" ::: "memory");                    \
    __asm__ __volatile__("s_barrier" ::: "memory");                             \
    _Pragma("unroll") for (int kk = 0; kk < 2; kk++) {                          \
      _Pragma("unroll") for (int mi = 0; mi < 4; mi++)                          \
        aF[kk][mi] = *(const bf16x8*)&At[aRow[mi] * 64 +                        \
                      (((kk * 4 + quad) ^ (aRow[mi] & 7)) * 8)];                \
      _Pragma("unroll") for (int ni = 0; ni < 2; ni++)                          \
        bF[kk][ni] = *(const bf16x8*)&Bt[bRow[ni] * 64 +                        \
                      (((kk * 4 + quad) ^ (bRow[ni] & 7)) * 8)];                \
    }                                                                           \
    if (nl) {                                                                   \
      stage_unit(A, m0, kn, Ax, tid);                                           \
      stage_unit(Bm, n0, kn, Bx, tid);                                          \
    }                                                                           \
    __asm__ __volatile__("s_waitcnt lgkmcnt(0)" ::: "memory");                  \
    __builtin_amdgcn_sched_barrier(0);                                          \
    __builtin_amdgcn_s_setprio(1);                                              \
    _Pragma("unroll") for (int kk = 0; kk < 2; kk++)                            \
      _Pragma("unroll") for (int mi = 0; mi < 4; mi++)                          \
        _Pragma("unroll") for (int ni = 0; ni < 2; ni++)                        \
          acc[mi][ni] = __builtin_amdgcn_mfma_f32_16x16x32_bf16(                \
              aF[kk][mi], bF[kk][ni], acc[mi][ni], 0, 0, 0);                    \
    __builtin_amdgcn_s_setprio(0);                                              \
    __builtin_amdgcn_sched_barrier(0);                                          \
    /* ---- P1: all mi x ni 2-3 (B-half1, reuse aF) ---- */                     \
    if (nl) { __asm__ __volatile__("s_waitcnt vmcnt(4)" ::: "memory"); }        \
    else    { __asm__ __volatile__("s_waitcnt vmcnt(0)" ::: "memory"); }        \
    __asm__ __volatile__("s_barrier" ::: "memory");                             \
    _Pragma("unroll") for (int kk = 0; kk < 2; kk++)                            \
      _Pragma("unroll") for (int ni = 0; ni < 2; ni++)                          \
        bF[kk][ni] = *(const bf16x8*)&Bt[bRow[2 + ni] * 64 +                    \
                      (((kk * 4 + quad) ^ (bRow[2 + ni] & 7)) * 8)];            \
    if (nl) stage_unit(Bm, n0 + 128, kn, Bx + 8192, tid);                       \
    __asm__ __volatile__("s_waitcnt lgkmcnt(0)" ::: "memory");                  \
    __builtin_amdgcn_sched_barrier(0);                                          \
    __builtin_amdgcn_s_setprio(1);                                              \
    _Pragma("unroll") for (int kk = 0; kk < 2; kk++)                            \
      _Pragma("unroll") for (int mi = 0; mi < 4; mi++)                          \
        _Pragma("unroll") for (int ni = 0; ni < 2; ni++)                        \
          acc[mi][2 + ni] = __builtin_amdgcn_mfma_f32_16x16x32_bf16(            \
              aF[kk][mi], bF[kk][ni], acc[mi][2 + ni], 0, 0, 0);                \
    __builtin_amdgcn_s_setprio(0);                                              \
    __builtin_amdgcn_sched_barrier(0);                                          \
  }

// ---------------- QKV GEMM (M=4096, N=6144, K=2048) + fused q/k scaling -----
// grid (32, 24) = 768 blocks = 3.0 exact rounds at 1 block/CU (96KB LDS).
__global__ __launch_bounds__(512, 2)
void gemm_qkv_rope(const u16* __restrict__ A, const u16* __restrict__ Bm,
                   u16* __restrict__ qo, u16* __restrict__ ko, u16* __restrict__ vo,
                   const float* __restrict__ fct) {
  __shared__ __align__(16) u16 Sh[49152];   // 96 KB
  GEMM_MAIN_LOOP

  // ---------------- epilogue ----------------
  // Block's 256 N-cols = 2 heads of ONE tensor (tensor boundary 2048 % 256 == 0).
  const int tensor = n0 >> 11;          // 0:q 1:k 2:v
  const int h0 = (n0 & 2047) >> 7;      // first of the two heads
  if (tensor < 2) {
    u16* dst = (tensor == 0) ? qo : ko;
#pragma unroll
    for (int mi = 0; mi < 4; mi++) {
      int rowM = wm * 64 + mi * 16;
#pragma unroll
      for (int r = 0; r < 4; r++) {
        int m = m0 + rowM + quad * 4 + r;
        int b = m >> 11, s = m & 2047;
        const float* fr = fct + s * 128;
#pragma unroll
        for (int ni = 0; ni < 4; ni++) {
          int colN = COLN(ni) + ln;                // 0..255 (interleaved map)
          int h = h0 + (colN >> 7);
          int j = colN & 127;                      // head-local col
          dst[((size_t)(b * NH + h) * SS + s) * HD + j] = f2bf(acc[mi][ni][r] * fr[j]);
        }
      }
    }
  } else {
    // V: transpose 128(s) x 256(hd over 2 heads) via LDS, 16B stores to (B,NH,HD,S)
    __syncthreads();                    // all waves done reading LA/LB
    u16* Tr = Sh;                       // 64KB: 256 hd-rows x 128 s-cols, swizzled
    const int b = m0 >> 11, s0 = m0 & 2047;
#pragma unroll
    for (int mi = 0; mi < 4; mi++) {
      int rowM = wm * 64 + mi * 16;
#pragma unroll
      for (int ni = 0; ni < 4; ni++) {
        int colN = COLN(ni) + ln;                  // hd-row 0..255 (colN&15 == ln)
#pragma unroll
        for (int r = 0; r < 4; r++) {
          int srel = rowM + quad * 4 + r;          // 0..127
          int ch = srel >> 3;                      // 16 chunks of 8 elems
          Tr[colN * 128 + ((ch ^ (colN & 15)) * 8) + (srel & 7)] = f2bf(acc[mi][ni][r]);
        }
      }
    }
    __syncthreads();
#pragma unroll
    for (int it = 0; it < 8; it++) {
      int slot = it * 512 + tid;                   // 4096 slots = 256 hd x 16 chunks
      int nloc = slot >> 4, c8 = slot & 15;
      uint4 val = *(const uint4*)&Tr[nloc * 128 + ((c8 ^ (nloc & 15)) * 8)];
      int h = h0 + (nloc >> 7), hd = nloc & 127;
      *(uint4*)(vo + ((size_t)(b * NH + h) * HD + hd) * SS + s0 + c8 * 8) = val;
    }
  }
}

// ---------------- Output GEMM (M=4096, N=2048, K=2048), fp32 epilogue --------
// grid (32, 8) = 256 blocks = 1.0 exact round at 1 block/CU.
__global__ __launch_bounds__(512, 2)
void gemm_out(const u16* __restrict__ A, const u16* __restrict__ Bm,
              float* __restrict__ C) {
  __shared__ __align__(16) u16 Sh[49152];   // 96 KB
  GEMM_MAIN_LOOP

#pragma unroll
  for (int mi = 0; mi < 4; mi++) {
    int rowM = wm * 64 + mi * 16;
#pragma unroll
    for (int r = 0; r < 4; r++) {
      int m = m0 + rowM + quad * 4 + r;
#pragma unroll
      for (int ni = 0; ni < 4; ni++) {
        int colN = COLN(ni) + ln;
        C[(size_t)m * DM + n0 + colN] = acc[mi][ni][r];
      }
    }
  }
}

// ---------------- Flash attention v4 ----------------
// grid (16, NH, B) = 512 blocks, 2 blocks/CU (LDS 72KB, launch_bounds(256,2)).
// Block bx handles 64-row q-tiles {bx, 31-bx} -> uniform 33 k-tile units/block.
// Q loaded direct global->registers (no LDS staging). K/V double-buffered,
// XOR-swizzled LDS for conflict-free ds_read_b128. P buffer 8KB, wave-private.
__global__ __launch_bounds__(256, 2)
void flash_attn(const u16* __restrict__ q, const u16* __restrict__ k,
                const u16* __restrict__ v, u16* __restrict__ o) {
  __shared__ __align__(16) u16 Ps[64 * 64];       // 8KB: P (wave-private 16-row slabs)
  __shared__ __align__(16) u16 Ks[2][64 * 128];   // 2 x 16KB
  __shared__ __align__(16) u16 Vs[2][128 * 64];   // 2 x 16KB (Vt: hd rows, k cols)
  const int tid = threadIdx.x;
  const int w = tid >> 6, lane = tid & 63, ln = lane & 15, quad = lane >> 4;
  const int hh = blockIdx.y, b = blockIdx.z;
  const size_t bh = (size_t)b * NH + hh;
  const u16* Kg = k + bh * SS * HD;
  const u16* Vg = v + bh * HD * SS;

  for (int half = 0; half < 2; half++) {
    const int T = half ? (31 - (int)blockIdx.x) : (int)blockIdx.x;
    const u16* Qg = q + bh * SS * HD + (size_t)T * 64 * HD;

    // Q -> registers, direct from global (read once; 4 x 16B/lane)
    bf16x8 qf[4];
#pragma unroll
    for (int kc = 0; kc < 4; kc++)
      qf[kc] = *(const bf16x8*)(Qg + (size_t)(w * 16 + ln) * HD + (kc * 4 + quad) * 8);

    __syncthreads();   // Ks/Vs free of previous tile's readers

    // prefetch kt=0 into buffer 0
#pragma unroll
    for (int i = 0; i < 4; i++) {
      int slot = i * 256 + tid;
      int r = slot >> 4, c = (slot & 15) ^ (r & 7);
      load_lds16(Kg + (size_t)r * HD + c * 8, (char*)Ks[0] + slot * 16);
    }
#pragma unroll
    for (int i = 0; i < 4; i++) {
      int slot = i * 256 + tid;
      int r = slot >> 3, c = (slot & 7) ^ (r & 7);
      load_lds16(Vg + (size_t)r * SS + c * 8, (char*)Vs[0] + slot * 16);
    }

    const f32x4 fz = {0.f, 0.f, 0.f, 0.f};
    float m_s[4], l_s[4];
    f32x4 accO[8];
#pragma unroll
    for (int r = 0; r < 4; r++) { m_s[r] = -1e30f; l_s[r] = 0.f; }
#pragma unroll
    for (int nt = 0; nt < 8; nt++) accO[nt] = fz;

    const int nkt = T + 1;
    const int qrb = T * 64 + w * 16;

    for (int kt = 0; kt < nkt; kt++) {
      const int cur = kt & 1;
      const int k0 = kt * 64;
      // drain the staging issued one iteration ago (latency already hidden)
      __asm__ __volatile__("s_waitcnt vmcnt(0)" ::: "memory");
      __syncthreads();
      if (kt + 1 < nkt) {   // prefetch next k-tile into the other buffer
        const int kn = k0 + 64;
#pragma unroll
        for (int i = 0; i < 4; i++) {
          int slot = i * 256 + tid;
          int r = slot >> 4, c = (slot & 15) ^ (r & 7);
          load_lds16(Kg + (size_t)(kn + r) * HD + c * 8, (char*)Ks[cur ^ 1] + slot * 16);
        }
#pragma unroll
        for (int i = 0; i < 4; i++) {
          int slot = i * 256 + tid;
          int r = slot >> 3, c = (slot & 7) ^ (r & 7);
          load_lds16(Vg + (size_t)r * SS + kn + c * 8, (char*)Vs[cur ^ 1] + slot * 16);
        }
      }

      // S = Q K^T  (16 q-rows x 64 k-cols per wave)
      f32x4 sc[4];
#pragma unroll
      for (int nt = 0; nt < 4; nt++) sc[nt] = fz;
#pragma unroll
      for (int kc = 0; kc < 4; kc++)
#pragma unroll
        for (int nt = 0; nt < 4; nt++) {
          bf16x8 bf = *(const bf16x8*)&Ks[cur][(nt * 16 + ln) * 128 + (((kc * 4 + quad) ^ (ln & 7)) * 8)];
          sc[nt] = __builtin_amdgcn_mfma_f32_16x16x32_bf16(qf[kc], bf, sc[nt], 0, 0, 0);
        }

      const bool partial = (kt == T);
#pragma unroll
      for (int nt = 0; nt < 4; nt++)
#pragma unroll
        for (int r = 0; r < 4; r++) {
          float val = sc[nt][r] * SCALE;
          if (partial && (k0 + nt * 16 + ln > qrb + quad * 4 + r)) val = -1e9f;
          sc[nt][r] = val;
        }

      // online softmax per row
#pragma unroll
      for (int r = 0; r < 4; r++) {
        float mx = fmaxf(fmaxf(sc[0][r], sc[1][r]), fmaxf(sc[2][r], sc[3][r]));
#pragma unroll
        for (int off = 1; off < 16; off <<= 1) mx = fmaxf(mx, __shfl_xor(mx, off));
        float mnew = fmaxf(m_s[r], mx);
        float alpha = exp2f((m_s[r] - mnew) * LOG2E);
        float rs = 0.f;
#pragma unroll
        for (int nt = 0; nt < 4; nt++) {
          float p = exp2f((sc[nt][r] - mnew) * LOG2E);
          sc[nt][r] = p;
          rs += p;
        }
#pragma unroll
        for (int off = 1; off < 16; off <<= 1) rs += __shfl_xor(rs, off);
        l_s[r] = l_s[r] * alpha + rs;
        m_s[r] = mnew;
#pragma unroll
        for (int nt = 0; nt < 8; nt++) accO[nt][r] *= alpha;
      }

      // P: C-layout -> LDS (swizzled, wave-private 16-row slab) -> A-layout
#pragma unroll
      for (int nt = 0; nt < 4; nt++)
#pragma unroll
        for (int r = 0; r < 4; r++) {
          int rr = w * 16 + quad * 4 + r;
          int j = nt * 16 + ln;
          Ps[rr * 64 + (((j >> 3) ^ (rr & 7)) * 8) + (j & 7)] = f2bf(sc[nt][r]);
        }
      __asm__ __volatile__("s_waitcnt lgkmcnt(0)" ::: "memory");

      bf16x8 pf[2];
#pragma unroll
      for (int kc = 0; kc < 2; kc++) {
        int rp = w * 16 + ln;
        pf[kc] = *(const bf16x8*)&Ps[rp * 64 + (((kc * 4 + quad) ^ (ln & 7)) * 8)];
      }

      // O += P V
#pragma unroll
      for (int kc = 0; kc < 2; kc++)
#pragma unroll
        for (int nt = 0; nt < 8; nt++) {
          bf16x8 vf = *(const bf16x8*)&Vs[cur][(nt * 16 + ln) * 64 + (((kc * 4 + quad) ^ (ln & 7)) * 8)];
          accO[nt] = __builtin_amdgcn_mfma_f32_16x16x32_bf16(pf[kc], vf, accO[nt], 0, 0, 0);
        }
    }

    // normalize + store (B, S, DM) bf16
#pragma unroll
    for (int r = 0; r < 4; r++) {
      float ilv = 1.f / l_s[r];
      int srow = T * 64 + w * 16 + quad * 4 + r;
      size_t base = ((size_t)b * SS + srow) * DM + hh * HD;
#pragma unroll
      for (int nt = 0; nt < 8; nt++)
        o[base + nt * 16 + ln] = f2bf(accO[nt][r] * ilv);
    }
  }
}

// ---------------- launch ----------------
extern "C" void kernel_launch(void* const* d_in, const int* in_sizes, int n_in,
                              void* d_out, int out_size, void* d_ws, size_t ws_size,
                              hipStream_t stream) {
  (void)in_sizes; (void)n_in; (void)out_size; (void)ws_size;
  const float* x  = (const float*)d_in[0];
  // d_in[1] = attention_mask (exact causal tril) — implemented analytically
  const float* Wq = (const float*)d_in[2];
  const float* Wk = (const float*)d_in[3];
  const float* Wv = (const float*)d_in[4];
  const float* Wd = (const float*)d_in[5];

  // Workspace (96 MiB):
  //   [0,16M) xb (reused as aob)  [16M,40M) wqkv  [40M..] fct then wdb
  //   [48M,64M) qb  [64M,80M) kb  [80M,96M) vtb
  char* ws = (char*)d_ws;
  u16* xb   = (u16*)(ws);
  u16* aob  = xb;
  u16* wqkv = (u16*)(ws + 16777216ull);
  float* fct = (float*)(ws + 41943040ull);
  u16* wdb  = (u16*)(ws + 41943040ull);
  u16* qb   = (u16*)(ws + 50331648ull);
  u16* kb   = (u16*)(ws + 67108864ull);
  u16* vtb  = (u16*)(ws + 83886080ull);

  cast_f32_bf16<<<8192, 256, 0, stream>>>(x,  xb, MM * KK);
  cast_f32_bf16<<<4096, 256, 0, stream>>>(Wq, wqkv,                   DM * KK);
  cast_f32_bf16<<<4096, 256, 0, stream>>>(Wk, wqkv + (size_t)DM*KK,   DM * KK);
  cast_f32_bf16<<<4096, 256, 0, stream>>>(Wv, wqkv + (size_t)2*DM*KK, DM * KK);
  rope_fct<<<1024, 256, 0, stream>>>(fct);

  gemm_qkv_rope<<<dim3(MM / 128, NQKV / 256), 512, 0, stream>>>(xb, wqkv, qb, kb, vtb, fct);

  cast_f32_bf16<<<4096, 256, 0, stream>>>(Wd, wdb, DM * KK);   // overwrites fct (dead)

  flash_attn<<<dim3(16, NH, BB), 256, 0, stream>>>(qb, kb, vtb, aob);
  gemm_out<<<dim3(MM / 128, DM / 256), 512, 0, stream>>>(aob, wdb, (float*)d_out);
}